// Round 4
// baseline (269.740 us; speedup 1.0000x reference)
//
#include <hip/hip_runtime.h>

constexpr int Hh = 2048;
constexpr int Ww = 2048;
constexpr int NN = Hh * Ww;
constexpr int W4 = Ww / 4;             // row stride in float4 (per stream)
constexpr int NN4 = NN / 4;            // plane stride in float4
constexpr int RAD = 10;                // size=21 -> radius 10
constexpr float EPSf = 1e-9f;
constexpr float MASK_THRf = 0.001f;
constexpr int BH = 16;                 // band height for vertical prefix
constexpr int NB = Hh / BH;            // 128 bands
constexpr int SEGW = 58;               // output float4 cols per wave (64 - 2*3 halo)
constexpr int NSEG = 9;                // ceil(W4 / SEGW)
constexpr int HBLOCKS = Hh * NSEG / 4; // 4608 blocks, 4 waves each
constexpr int VROW = W4 * 3;           // interleaved row stride in float4 (1536)

__device__ inline float rcpf(float x) { return __builtin_amdgcn_rcpf(x); }

__device__ inline float waveReduce(float v) {
    #pragma unroll
    for (int o = 32; o > 0; o >>= 1) v += __shfl_down(v, o, 64);
    return v;
}

__device__ inline float4 f4zero() { float4 z; z.x = z.y = z.z = z.w = 0.f; return z; }
__device__ inline float4 f4add(float4 a, float4 b) {
    float4 r; r.x = a.x + b.x; r.y = a.y + b.y; r.z = a.z + b.z; r.w = a.w + b.w; return r;
}
__device__ inline float4 f4sub(float4 a, float4 b) {
    float4 r; r.x = a.x - b.x; r.y = a.y - b.y; r.z = a.z - b.z; r.w = a.w - b.w; return r;
}
__device__ inline void add4(float4& a, const float4 b) { a.x += b.x; a.y += b.y; a.z += b.z; a.w += b.w; }

// Direct 21-tap horizontal box of v (zero outside the wave's halo) via
// neighbor-lane shuffles. Valid only for lanes 3..60 (halo lanes discarded).
__device__ inline float4 hbox(float4 v, int lane) {
    float S = v.x + v.y + v.z + v.w;
    float Sm2 = __shfl(S, lane - 2, 64);
    float Sm1 = __shfl(S, lane - 1, 64);
    float Sp1 = __shfl(S, lane + 1, 64);
    float Sp2 = __shfl(S, lane + 2, 64);
    float T5 = Sm2 + Sm1 + S + Sp1 + Sp2;
    float wm3 = __shfl(v.w, lane - 3, 64);
    float zm3 = __shfl(v.z, lane - 3, 64);
    float xm2 = __shfl(v.x, lane - 2, 64);
    float wp2 = __shfl(v.w, lane + 2, 64);
    float xp3 = __shfl(v.x, lane + 3, 64);
    float yp3 = __shfl(v.y, lane + 3, 64);
    float4 r;
    r.y = T5 + wm3;
    r.z = T5 + xp3;
    r.x = r.y + zm3 - wp2;
    r.w = r.z + yp3 - xm2;
    return r;
}

// Interleaved layout: V[(row*W4 + col4)*3 + j], j = 0:mask, 1:b/P, 2:b2/Q.
// All consumers read the 3 slots at one (row,col) -> one 3KB contiguous burst
// per region instead of 3 scattered 1KB granules (stream-count theory, R3).

// ---------------- K1p: band-local vertical prefix of (mask, b, b2) ----------------
__global__ __launch_bounds__(256) void k1p(
        const float* __restrict__ I, const float* __restrict__ B,
        float* __restrict__ V, float* __restrict__ T) {
    int x4 = blockIdx.x * 256 + threadIdx.x;     // float4 column
    int y0 = blockIdx.y * BH;
    const float4* I4 = (const float4*)I;
    const float4* B4 = (const float4*)B;
    float4* V4 = (float4*)V;
    float4* T4 = (float4*)T;
    float4 am = f4zero(), ab = f4zero(), ab2 = f4zero();
    #pragma unroll
    for (int r = 0; r < BH; ++r) {
        int idx = (y0 + r) * W4 + x4;
        float4 iv = I4[idx], bv = B4[idx];
        am.x += (iv.x > MASK_THRf) ? 1.f : 0.f;
        am.y += (iv.y > MASK_THRf) ? 1.f : 0.f;
        am.z += (iv.z > MASK_THRf) ? 1.f : 0.f;
        am.w += (iv.w > MASK_THRf) ? 1.f : 0.f;
        ab.x += bv.x; ab.y += bv.y; ab.z += bv.z; ab.w += bv.w;
        ab2.x += bv.x * bv.x; ab2.y += bv.y * bv.y;
        ab2.z += bv.z * bv.z; ab2.w += bv.w * bv.w;
        int o = idx * 3;
        V4[o + 0] = am; V4[o + 1] = ab; V4[o + 2] = ab2;
    }
    int t = (blockIdx.y * W4 + x4) * 3;
    T4[t + 0] = am; T4[t + 1] = ab; T4[t + 2] = ab2;
}

// ---------------- koff: exclusive prefix over band totals, all 1536 flat cols ----------------
__global__ __launch_bounds__(256) void koff(
        const float* __restrict__ T, float* __restrict__ O) {
    int col = blockIdx.x * 256 + threadIdx.x;    // flat interleaved column, 0..1535
    const float4* T4 = (const float4*)T;
    float4* O4 = (float4*)O;
    float4 acc = f4zero();
    #pragma unroll 8
    for (int b = 0; b < NB; ++b) {
        O4[b * VROW + col] = acc;
        add4(acc, T4[b * VROW + col]);
    }
}

// koff2: same, but only slots 1,2 (P,Q) — preserves slot-0 (mask) offsets in O.
__global__ __launch_bounds__(256) void koff2(
        const float* __restrict__ T, float* __restrict__ O) {
    int c4 = blockIdx.x * 256 + threadIdx.x;     // 0..1023 -> slots {1,2} of 512 cols
    int col = (c4 >> 1) * 3 + 1 + (c4 & 1);
    const float4* T4 = (const float4*)T;
    float4* O4 = (float4*)O;
    float4 acc = f4zero();
    #pragma unroll 8
    for (int b = 0; b < NB; ++b) {
        O4[b * VROW + col] = acc;
        add4(acc, T4[b * VROW + col]);
    }
}

// ---------------- K2s: one-shot segment h-box + phase-A reductions ----------------
__device__ inline void k2_pix(float bm, float bb, float bb2, float Iv, float ev,
                              float u0, float u1, float u2, float u3, float* a) {
    float rn = rcpf(bm + EPSf);
    float bK = bb * rn;
    float b2K = bb2 * rn;
    float p0 = u0 * u0, p1 = u1 * u1, p2 = u2 * u2, p3 = u3 * u3;
    a[0] += Iv * p0;
    a[1] += p0;
    float A = (Iv - ev) * bK;
    a[2] += A * p1; a[3] += A * p2; a[4] += A * p3;
    a[5] += b2K * p1; a[6] += b2K * p2; a[7] += b2K * p3;
}

__global__ __launch_bounds__(256) void k2s(
        const float* __restrict__ V, const float* __restrict__ O,
        const float* __restrict__ I, const float* __restrict__ E, const float* __restrict__ U,
        float* __restrict__ partA) {
    int lane = threadIdx.x & 63;
    int wid = blockIdx.x * 4 + (threadIdx.x >> 6);
    int row = wid / NSEG;
    int seg = wid - row * NSEG;
    int xc = seg * SEGW - 3 + lane;              // float4 column this lane loads
    bool inb = (unsigned)xc < (unsigned)W4;
    int xl = inb ? xc : 0;

    int yup = row + RAD; if (yup > Hh - 1) yup = Hh - 1;
    int ydn = row - RAD - 1;
    bool hasDn = ydn >= 0;
    int upBase = (yup * W4 + xl) * 3;
    int dnBase = ((hasDn ? ydn : 0) * W4 + xl) * 3;
    int obUp = ((yup / BH) * W4 + xl) * 3;
    int obDn = (((hasDn ? ydn : 0) / BH) * W4 + xl) * 3;

    const float4* V4 = (const float4*)V;
    const float4* O4 = (const float4*)O;

    float4 vm = f4zero(), vb = f4zero(), vq = f4zero();
    if (inb) {
        vm = f4add(V4[upBase + 0], O4[obUp + 0]);
        vb = f4add(V4[upBase + 1], O4[obUp + 1]);
        vq = f4add(V4[upBase + 2], O4[obUp + 2]);
        if (hasDn) {
            vm = f4sub(vm, f4add(V4[dnBase + 0], O4[obDn + 0]));
            vb = f4sub(vb, f4add(V4[dnBase + 1], O4[obDn + 1]));
            vq = f4sub(vq, f4add(V4[dnBase + 2], O4[obDn + 2]));
        }
    }

    float4 bm = hbox(vm, lane);
    float4 bb = hbox(vb, lane);
    float4 bq = hbox(vq, lane);

    float a[8] = {0, 0, 0, 0, 0, 0, 0, 0};
    if (inb && lane >= 3 && lane <= 60) {
        const float4* I4 = (const float4*)I;
        const float4* E4 = (const float4*)E;
        const float4* U0 = (const float4*)U;
        const float4* U1 = U0 + NN4;
        const float4* U2 = U1 + NN4;
        const float4* U3 = U2 + NN4;
        int xo = row * W4 + xc;
        float4 Iv = I4[xo], Ev = E4[xo];
        float4 u0 = U0[xo], u1 = U1[xo], u2 = U2[xo], u3 = U3[xo];
        k2_pix(bm.x, bb.x, bq.x, Iv.x, Ev.x, u0.x, u1.x, u2.x, u3.x, a);
        k2_pix(bm.y, bb.y, bq.y, Iv.y, Ev.y, u0.y, u1.y, u2.y, u3.y, a);
        k2_pix(bm.z, bb.z, bq.z, Iv.z, Ev.z, u0.z, u1.z, u2.z, u3.z, a);
        k2_pix(bm.w, bb.w, bq.w, Iv.w, Ev.w, u0.w, u1.w, u2.w, u3.w, a);
    }

    __shared__ float sred[4][8];
    int wave = threadIdx.x >> 6;
    #pragma unroll
    for (int k = 0; k < 8; ++k) a[k] = waveReduce(a[k]);
    if (lane == 0) {
        #pragma unroll
        for (int k = 0; k < 8; ++k) sred[wave][k] = a[k];
    }
    __syncthreads();
    if (threadIdx.x < 8) {
        float s = sred[0][threadIdx.x] + sred[1][threadIdx.x] +
                  sred[2][threadIdx.x] + sred[3][threadIdx.x];
        partA[(blockIdx.x << 3) + threadIdx.x] = s;
    }
}

// ---------------- K3: reduce per-block partials (HBLOCKS x 8), compute v ----------------
__global__ __launch_bounds__(1024) void k3_v(const float* __restrict__ partA, float* __restrict__ vV) {
    __shared__ float s[1024];
    int tid = threadIdx.x;
    float acc = 0.f;
    #pragma unroll
    for (int j = 0; j < (HBLOCKS * 8) / 1024; ++j) acc += partA[tid + j * 1024];
    s[tid] = acc;
    __syncthreads();
    #pragma unroll
    for (int st = 512; st >= 8; st >>= 1) {
        if (tid < st) s[tid] += s[tid + st];
        __syncthreads();
    }
    if (tid == 0) {
        vV[0] = s[0] / (s[1] + EPSf);
        vV[1] = s[2] / (s[5] + EPSf);
        vV[2] = s[3] / (s[6] + EPSf);
        vV[3] = s[4] / (s[7] + EPSf);
    }
}

// ---------------- K4p: band-local vertical prefix of (P, Q) into V slots 1,2 ----------------
__global__ __launch_bounds__(256) void k4p(
        const float* __restrict__ I, const float* __restrict__ E, const float* __restrict__ U,
        const float* __restrict__ vV,
        float* __restrict__ V, float* __restrict__ T) {
    int x4 = blockIdx.x * 256 + threadIdx.x;
    int y0 = blockIdx.y * BH;
    float v0 = vV[0], v1 = vV[1], v2 = vV[2], v3 = vV[3];
    float w0 = v0 * v0, w1 = v1 * v1, w2 = v2 * v2, w3 = v3 * v3;
    const float4* I4 = (const float4*)I;
    const float4* E4 = (const float4*)E;
    const float4* U0 = (const float4*)U;
    const float4* U1 = U0 + NN4;
    const float4* U2 = U1 + NN4;
    const float4* U3 = U2 + NN4;
    float4* V4 = (float4*)V;
    float4* T4 = (float4*)T;
    float4 aP = f4zero(), aQ = f4zero();
    #pragma unroll
    for (int r = 0; r < BH; ++r) {
        int idx = (y0 + r) * W4 + x4;
        float4 Iv = I4[idx], Ev = E4[idx];
        float4 a0 = U0[idx], a1 = U1[idx], a2 = U2[idx], a3 = U3[idx];
        float p0, p1, p2, p3;
        p0 = a0.x * a0.x; p1 = a1.x * a1.x; p2 = a2.x * a2.x; p3 = a3.x * a3.x;
        aP.x += (Iv.x - Ev.x) * (v0 * p0 + v1 * p1 + v2 * p2 + v3 * p3);
        aQ.x += w0 * p0 + w1 * p1 + w2 * p2 + w3 * p3;
        p0 = a0.y * a0.y; p1 = a1.y * a1.y; p2 = a2.y * a2.y; p3 = a3.y * a3.y;
        aP.y += (Iv.y - Ev.y) * (v0 * p0 + v1 * p1 + v2 * p2 + v3 * p3);
        aQ.y += w0 * p0 + w1 * p1 + w2 * p2 + w3 * p3;
        p0 = a0.z * a0.z; p1 = a1.z * a1.z; p2 = a2.z * a2.z; p3 = a3.z * a3.z;
        aP.z += (Iv.z - Ev.z) * (v0 * p0 + v1 * p1 + v2 * p2 + v3 * p3);
        aQ.z += w0 * p0 + w1 * p1 + w2 * p2 + w3 * p3;
        p0 = a0.w * a0.w; p1 = a1.w * a1.w; p2 = a2.w * a2.w; p3 = a3.w * a3.w;
        aP.w += (Iv.w - Ev.w) * (v0 * p0 + v1 * p1 + v2 * p2 + v3 * p3);
        aQ.w += w0 * p0 + w1 * p1 + w2 * p2 + w3 * p3;
        int o = idx * 3;
        V4[o + 1] = aP; V4[o + 2] = aQ;          // slot 0 (mask prefix) preserved
    }
    int t = (blockIdx.y * W4 + x4) * 3;
    T4[t + 1] = aP; T4[t + 2] = aQ;              // slot 0 (mask totals) preserved
}

// ---------------- K5s: one-shot segment h-box of (m,P,Q) + masked combine + loss ----------------
__global__ __launch_bounds__(256) void k5s(
        const float* __restrict__ V, const float* __restrict__ O,
        const float* __restrict__ I, const float* __restrict__ B,
        float* __restrict__ partL) {
    int lane = threadIdx.x & 63;
    int wid = blockIdx.x * 4 + (threadIdx.x >> 6);
    int row = wid / NSEG;
    int seg = wid - row * NSEG;
    int xc = seg * SEGW - 3 + lane;
    bool inb = (unsigned)xc < (unsigned)W4;
    int xl = inb ? xc : 0;

    int yup = row + RAD; if (yup > Hh - 1) yup = Hh - 1;
    int ydn = row - RAD - 1;
    bool hasDn = ydn >= 0;
    int upBase = (yup * W4 + xl) * 3;
    int dnBase = ((hasDn ? ydn : 0) * W4 + xl) * 3;
    int obUp = ((yup / BH) * W4 + xl) * 3;
    int obDn = (((hasDn ? ydn : 0) / BH) * W4 + xl) * 3;

    const float4* V4 = (const float4*)V;
    const float4* O4 = (const float4*)O;

    float4 vM = f4zero(), vP = f4zero(), vQ = f4zero();
    if (inb) {
        vM = f4add(V4[upBase + 0], O4[obUp + 0]);
        vP = f4add(V4[upBase + 1], O4[obUp + 1]);
        vQ = f4add(V4[upBase + 2], O4[obUp + 2]);
        if (hasDn) {
            vM = f4sub(vM, f4add(V4[dnBase + 0], O4[obDn + 0]));
            vP = f4sub(vP, f4add(V4[dnBase + 1], O4[obDn + 1]));
            vQ = f4sub(vQ, f4add(V4[dnBase + 2], O4[obDn + 2]));
        }
    }

    float4 bM = hbox(vM, lane);
    float4 bP = hbox(vP, lane);
    float4 bQ = hbox(vQ, lane);

    float a = 0.f;
    if (inb && lane >= 3 && lane <= 60) {
        const float4* I4 = (const float4*)I;
        const float4* B4 = (const float4*)B;
        int xo = row * W4 + xc;
        float4 Iv = I4[xo], Bv = B4[xo];
        {
            float rn = rcpf(bM.x + EPSf);
            float bd = bP.x * rn, db = bQ.x * rn;
            float m = (Iv.x > MASK_THRf) ? 1.f : 0.f;
            bd = bd * m + (1.f - m); db = db * m + (1.f - m);
            float d = Bv.x - bd * rcpf(db + EPSf); a += d * d;
        }
        {
            float rn = rcpf(bM.y + EPSf);
            float bd = bP.y * rn, db = bQ.y * rn;
            float m = (Iv.y > MASK_THRf) ? 1.f : 0.f;
            bd = bd * m + (1.f - m); db = db * m + (1.f - m);
            float d = Bv.y - bd * rcpf(db + EPSf); a += d * d;
        }
        {
            float rn = rcpf(bM.z + EPSf);
            float bd = bP.z * rn, db = bQ.z * rn;
            float m = (Iv.z > MASK_THRf) ? 1.f : 0.f;
            bd = bd * m + (1.f - m); db = db * m + (1.f - m);
            float d = Bv.z - bd * rcpf(db + EPSf); a += d * d;
        }
        {
            float rn = rcpf(bM.w + EPSf);
            float bd = bP.w * rn, db = bQ.w * rn;
            float m = (Iv.w > MASK_THRf) ? 1.f : 0.f;
            bd = bd * m + (1.f - m); db = db * m + (1.f - m);
            float d = Bv.w - bd * rcpf(db + EPSf); a += d * d;
        }
    }

    a = waveReduce(a);
    __shared__ float sred[4];
    int wave = threadIdx.x >> 6;
    if (lane == 0) sred[wave] = a;
    __syncthreads();
    if (threadIdx.x == 0) {
        partL[blockIdx.x] = sred[0] + sred[1] + sred[2] + sred[3];
    }
}

// ---------------- K6: reduce per-block loss partials, write mean ----------------
__global__ __launch_bounds__(1024) void k6_out(const float* __restrict__ partL, float* __restrict__ out) {
    __shared__ float s[1024];
    int tid = threadIdx.x;
    float acc = 0.f;
    for (int c = tid; c < HBLOCKS; c += 1024) acc += partL[c];
    s[tid] = acc;
    __syncthreads();
    #pragma unroll
    for (int st = 512; st >= 1; st >>= 1) {
        if (tid < st) s[tid] += s[tid + st];
        __syncthreads();
    }
    if (tid == 0) out[0] = s[0] / (float)NN;
}

extern "C" void kernel_launch(void* const* d_in, const int* in_sizes, int n_in,
                              void* d_out, int out_size, void* d_ws, size_t ws_size,
                              hipStream_t stream) {
    const float* I = (const float*)d_in[0];
    const float* U = (const float*)d_in[1];
    const float* B = (const float*)d_in[2];
    const float* E = (const float*)d_in[3];
    // p=2, size=21 fixed by setup_inputs; hard-coded.

    float* V  = (float*)d_ws;           // interleaved vertical prefix [row][512][3] float4 (3*NN floats)
    float* T  = V + 3 * NN;             // interleaved band totals  [band][512][3]  (3*NB*Ww floats)
    float* O  = T + 3 * NB * Ww;        // interleaved band offsets [band][512][3]
    float* vV = O + 3 * NB * Ww;        // v0..v3

    // Scratch reuse inside T (timeline):
    //  k1p writes T -> koff#1 consumes all slots -> slot use is over until k4p.
    //  partA (k2s, 36864 floats) lives at T; k3_v consumes it BEFORE k4p rewrites
    //  T slots 1,2. koff2 reads only slots 1,2. partL (k5s, 4608 floats) reuses T
    //  after koff2 has consumed it.
    float* partA = T;
    float* partL = T;

    dim3 blk(256);
    dim3 gband(2, NB);                  // 256 blocks for band-prefix kernels

    k1p<<<gband, blk, 0, stream>>>(I, B, V, T);
    koff<<<6, blk, 0, stream>>>(T, O);                       // all 1536 flat columns
    k2s<<<HBLOCKS, blk, 0, stream>>>(V, O, I, E, U, partA);
    k3_v<<<1, 1024, 0, stream>>>(partA, vV);
    k4p<<<gband, blk, 0, stream>>>(I, E, U, vV, V, T);       // writes slots 1,2 only
    koff2<<<4, blk, 0, stream>>>(T, O);                      // P,Q offsets; mask offsets preserved
    k5s<<<HBLOCKS, blk, 0, stream>>>(V, O, I, B, partL);
    k6_out<<<1, 1024, 0, stream>>>(partL, (float*)d_out);
}

// Round 5
// 249.919 us; speedup vs baseline: 1.0793x; 1.0793x over previous
//
#include <hip/hip_runtime.h>

constexpr int Hh = 2048;
constexpr int Ww = 2048;
constexpr int NN = Hh * Ww;
constexpr int W4 = Ww / 4;             // row stride in float4
constexpr int NN4 = NN / 4;            // plane stride in float4
constexpr int RAD = 10;                // size=21 -> radius 10
constexpr float EPSf = 1e-9f;
constexpr float MASK_THRf = 0.001f;
constexpr int SEGW = 58;               // output float4 cols per wave (64 - 2*3 halo)
constexpr int NSEG = 9;                // ceil(W4 / SEGW)
constexpr int BH = 16;                 // rows walked per wave (band height)
constexpr int NBAND = Hh / BH;         // 128 bands
constexpr int NWAVE = NSEG * NBAND;    // 1152 wave-items (1-wave blocks)

__device__ inline float rcpf(float x) { return __builtin_amdgcn_rcpf(x); }

__device__ inline float waveReduce(float v) {
    #pragma unroll
    for (int o = 32; o > 0; o >>= 1) v += __shfl_down(v, o, 64);
    return v;
}

__device__ inline float4 f4zero() { float4 z; z.x = z.y = z.z = z.w = 0.f; return z; }

// Direct 21-tap horizontal box of v (zero outside the wave's halo) via
// neighbor-lane shuffles. Valid only for lanes 3..60 (halo lanes discarded).
__device__ inline float4 hbox(float4 v, int lane) {
    float S = v.x + v.y + v.z + v.w;
    float Sm2 = __shfl(S, lane - 2, 64);
    float Sm1 = __shfl(S, lane - 1, 64);
    float Sp1 = __shfl(S, lane + 1, 64);
    float Sp2 = __shfl(S, lane + 2, 64);
    float T5 = Sm2 + Sm1 + S + Sp1 + Sp2;
    float wm3 = __shfl(v.w, lane - 3, 64);
    float zm3 = __shfl(v.z, lane - 3, 64);
    float xm2 = __shfl(v.x, lane - 2, 64);
    float wp2 = __shfl(v.w, lane + 2, 64);
    float xp3 = __shfl(v.x, lane + 3, 64);
    float yp3 = __shfl(v.y, lane + 3, 64);
    float4 r;
    r.y = T5 + wm3;
    r.z = T5 + xp3;
    r.x = r.y + zm3 - wp2;
    r.w = r.z + yp3 - xm2;
    return r;
}

// window accumulate helpers (mask, b, b2) — add and subtract produce the exact
// same f(row) bit pattern, so the sliding window cancels exactly per term.
__device__ inline void wAddA(float4& sm, float4& sb, float4& sq, float4 iv, float4 bv) {
    sm.x += (iv.x > MASK_THRf) ? 1.f : 0.f;
    sm.y += (iv.y > MASK_THRf) ? 1.f : 0.f;
    sm.z += (iv.z > MASK_THRf) ? 1.f : 0.f;
    sm.w += (iv.w > MASK_THRf) ? 1.f : 0.f;
    sb.x += bv.x; sb.y += bv.y; sb.z += bv.z; sb.w += bv.w;
    sq.x += bv.x * bv.x; sq.y += bv.y * bv.y; sq.z += bv.z * bv.z; sq.w += bv.w * bv.w;
}
__device__ inline void wSubA(float4& sm, float4& sb, float4& sq, float4 iv, float4 bv) {
    sm.x -= (iv.x > MASK_THRf) ? 1.f : 0.f;
    sm.y -= (iv.y > MASK_THRf) ? 1.f : 0.f;
    sm.z -= (iv.z > MASK_THRf) ? 1.f : 0.f;
    sm.w -= (iv.w > MASK_THRf) ? 1.f : 0.f;
    sb.x -= bv.x; sb.y -= bv.y; sb.z -= bv.z; sb.w -= bv.w;
    sq.x -= bv.x * bv.x; sq.y -= bv.y * bv.y; sq.z -= bv.z * bv.z; sq.w -= bv.w * bv.w;
}

__device__ inline void k2_pix(float bm, float bb, float bb2, float Iv, float ev,
                              float u0, float u1, float u2, float u3, float* a) {
    float rn = rcpf(bm + EPSf);
    float bK = bb * rn;
    float b2K = bb2 * rn;
    float p0 = u0 * u0, p1 = u1 * u1, p2 = u2 * u2, p3 = u3 * u3;
    a[0] += Iv * p0;
    a[1] += p0;
    float A = (Iv - ev) * bK;
    a[2] += A * p1; a[3] += A * p2; a[4] += A * p3;
    a[5] += b2K * p1; a[6] += b2K * p2; a[7] += b2K * p3;
}

// ---------------- kA: fused vertical-sliding-window + h-box + phase-A reductions ----------------
// One wave per (strip, band). Streams I,B down the band (head reads = HBM,
// tail re-reads 21 rows later = cache). No vertical-prefix intermediates.
__global__ __launch_bounds__(64) void kA(
        const float* __restrict__ I, const float* __restrict__ B,
        const float* __restrict__ E, const float* __restrict__ U,
        float* __restrict__ partA) {
    int lane = threadIdx.x;
    int wid = blockIdx.x;
    int strip = wid % NSEG;              // adjacent blocks share a band -> row locality
    int band = wid / NSEG;
    int xc = strip * SEGW - 3 + lane;
    bool inb = (unsigned)xc < (unsigned)W4;
    int xl = inb ? xc : 0;
    int y0 = band * BH;

    const float4* I4 = (const float4*)I;
    const float4* B4 = (const float4*)B;
    const float4* E4 = (const float4*)E;
    const float4* U0 = (const float4*)U;
    const float4* U1 = U0 + NN4;
    const float4* U2 = U1 + NN4;
    const float4* U3 = U2 + NN4;

    float4 sm = f4zero(), sb = f4zero(), sq = f4zero();
    // prime with window(y0-1) = rows [y0-11, y0+9]; OOB rows are zero (conv zero-pad)
    for (int r = y0 - RAD - 1; r <= y0 + RAD - 1; ++r) {
        if ((unsigned)r < (unsigned)Hh) {
            float4 iv = I4[r * W4 + xl], bv = B4[r * W4 + xl];
            wAddA(sm, sb, sq, iv, bv);
        }
    }

    float a[8] = {0, 0, 0, 0, 0, 0, 0, 0};
    for (int y = y0; y < y0 + BH; ++y) {
        int hd = y + RAD, tl = y - RAD - 1;
        if (hd < Hh) {
            float4 iv = I4[hd * W4 + xl], bv = B4[hd * W4 + xl];
            wAddA(sm, sb, sq, iv, bv);
        }
        if (tl >= 0) {                   // exact re-read: cache hit, exact cancellation
            float4 iv = I4[tl * W4 + xl], bv = B4[tl * W4 + xl];
            wSubA(sm, sb, sq, iv, bv);
        }
        float4 vm = inb ? sm : f4zero();
        float4 vb = inb ? sb : f4zero();
        float4 vq = inb ? sq : f4zero();
        float4 bm = hbox(vm, lane);
        float4 bb = hbox(vb, lane);
        float4 bq = hbox(vq, lane);
        if (inb && lane >= 3 && lane <= 60) {
            int xo = y * W4 + xc;
            float4 Iv = I4[xo], Ev = E4[xo];   // I[y] is inside the window: cache hit
            float4 u0 = U0[xo], u1 = U1[xo], u2 = U2[xo], u3 = U3[xo];
            k2_pix(bm.x, bb.x, bq.x, Iv.x, Ev.x, u0.x, u1.x, u2.x, u3.x, a);
            k2_pix(bm.y, bb.y, bq.y, Iv.y, Ev.y, u0.y, u1.y, u2.y, u3.y, a);
            k2_pix(bm.z, bb.z, bq.z, Iv.z, Ev.z, u0.z, u1.z, u2.z, u3.z, a);
            k2_pix(bm.w, bb.w, bq.w, Iv.w, Ev.w, u0.w, u1.w, u2.w, u3.w, a);
        }
    }

    #pragma unroll
    for (int k = 0; k < 8; ++k) a[k] = waveReduce(a[k]);
    if (lane == 0) {
        float4 r0, r1;
        r0.x = a[0]; r0.y = a[1]; r0.z = a[2]; r0.w = a[3];
        r1.x = a[4]; r1.y = a[5]; r1.z = a[6]; r1.w = a[7];
        ((float4*)partA)[wid * 2]     = r0;
        ((float4*)partA)[wid * 2 + 1] = r1;
    }
}

// ---------------- k3: reduce per-wave partials (NWAVE x 8), compute v ----------------
__global__ __launch_bounds__(1024) void k3_v(const float* __restrict__ partA, float* __restrict__ vV) {
    __shared__ float s[1024];
    int tid = threadIdx.x;
    float acc = 0.f;
    #pragma unroll
    for (int j = 0; j < (NWAVE * 8) / 1024; ++j) acc += partA[tid + j * 1024];
    s[tid] = acc;
    __syncthreads();
    #pragma unroll
    for (int st = 512; st >= 8; st >>= 1) {
        if (tid < st) s[tid] += s[tid + st];
        __syncthreads();
    }
    if (tid == 0) {
        vV[0] = s[0] / (s[1] + EPSf);
        vV[1] = s[2] / (s[5] + EPSf);
        vV[2] = s[3] / (s[6] + EPSf);
        vV[3] = s[4] / (s[7] + EPSf);
    }
}

// ---------------- kP: elementwise P = (I-e)*sum(v*u^2), Q = sum(v^2*u^2) ----------------
__global__ __launch_bounds__(256) void kP(
        const float* __restrict__ I, const float* __restrict__ E, const float* __restrict__ U,
        const float* __restrict__ vV,
        float* __restrict__ P, float* __restrict__ Q) {
    int idx = blockIdx.x * 256 + threadIdx.x;    // float4 index, grid covers NN4 exactly
    float v0 = vV[0], v1 = vV[1], v2 = vV[2], v3 = vV[3];
    float w0 = v0 * v0, w1 = v1 * v1, w2 = v2 * v2, w3 = v3 * v3;
    const float4* I4 = (const float4*)I;
    const float4* E4 = (const float4*)E;
    const float4* U0 = (const float4*)U;
    const float4* U1 = U0 + NN4;
    const float4* U2 = U1 + NN4;
    const float4* U3 = U2 + NN4;
    float4 Iv = I4[idx], Ev = E4[idx];
    float4 a0 = U0[idx], a1 = U1[idx], a2 = U2[idx], a3 = U3[idx];
    float4 p, q;
    float p0, p1, p2, p3;
    p0 = a0.x * a0.x; p1 = a1.x * a1.x; p2 = a2.x * a2.x; p3 = a3.x * a3.x;
    p.x = (Iv.x - Ev.x) * (v0 * p0 + v1 * p1 + v2 * p2 + v3 * p3);
    q.x = w0 * p0 + w1 * p1 + w2 * p2 + w3 * p3;
    p0 = a0.y * a0.y; p1 = a1.y * a1.y; p2 = a2.y * a2.y; p3 = a3.y * a3.y;
    p.y = (Iv.y - Ev.y) * (v0 * p0 + v1 * p1 + v2 * p2 + v3 * p3);
    q.y = w0 * p0 + w1 * p1 + w2 * p2 + w3 * p3;
    p0 = a0.z * a0.z; p1 = a1.z * a1.z; p2 = a2.z * a2.z; p3 = a3.z * a3.z;
    p.z = (Iv.z - Ev.z) * (v0 * p0 + v1 * p1 + v2 * p2 + v3 * p3);
    q.z = w0 * p0 + w1 * p1 + w2 * p2 + w3 * p3;
    p0 = a0.w * a0.w; p1 = a1.w * a1.w; p2 = a2.w * a2.w; p3 = a3.w * a3.w;
    p.w = (Iv.w - Ev.w) * (v0 * p0 + v1 * p1 + v2 * p2 + v3 * p3);
    q.w = w0 * p0 + w1 * p1 + w2 * p2 + w3 * p3;
    ((float4*)P)[idx] = p;
    ((float4*)Q)[idx] = q;
}

// ---------------- kB: fused sliding-window over (P,Q,mask) + h-box + loss ----------------
__global__ __launch_bounds__(64) void kB(
        const float* __restrict__ P, const float* __restrict__ Q,
        const float* __restrict__ I, const float* __restrict__ B,
        float* __restrict__ partL) {
    int lane = threadIdx.x;
    int wid = blockIdx.x;
    int strip = wid % NSEG;
    int band = wid / NSEG;
    int xc = strip * SEGW - 3 + lane;
    bool inb = (unsigned)xc < (unsigned)W4;
    int xl = inb ? xc : 0;
    int y0 = band * BH;

    const float4* P4 = (const float4*)P;
    const float4* Q4 = (const float4*)Q;
    const float4* I4 = (const float4*)I;
    const float4* B4 = (const float4*)B;

    float4 sp = f4zero(), sqq = f4zero(), sm = f4zero();
    for (int r = y0 - RAD - 1; r <= y0 + RAD - 1; ++r) {
        if ((unsigned)r < (unsigned)Hh) {
            float4 pv = P4[r * W4 + xl], qv = Q4[r * W4 + xl], iv = I4[r * W4 + xl];
            sp.x += pv.x; sp.y += pv.y; sp.z += pv.z; sp.w += pv.w;
            sqq.x += qv.x; sqq.y += qv.y; sqq.z += qv.z; sqq.w += qv.w;
            sm.x += (iv.x > MASK_THRf) ? 1.f : 0.f;
            sm.y += (iv.y > MASK_THRf) ? 1.f : 0.f;
            sm.z += (iv.z > MASK_THRf) ? 1.f : 0.f;
            sm.w += (iv.w > MASK_THRf) ? 1.f : 0.f;
        }
    }

    float a = 0.f;
    for (int y = y0; y < y0 + BH; ++y) {
        int hd = y + RAD, tl = y - RAD - 1;
        if (hd < Hh) {
            float4 pv = P4[hd * W4 + xl], qv = Q4[hd * W4 + xl], iv = I4[hd * W4 + xl];
            sp.x += pv.x; sp.y += pv.y; sp.z += pv.z; sp.w += pv.w;
            sqq.x += qv.x; sqq.y += qv.y; sqq.z += qv.z; sqq.w += qv.w;
            sm.x += (iv.x > MASK_THRf) ? 1.f : 0.f;
            sm.y += (iv.y > MASK_THRf) ? 1.f : 0.f;
            sm.z += (iv.z > MASK_THRf) ? 1.f : 0.f;
            sm.w += (iv.w > MASK_THRf) ? 1.f : 0.f;
        }
        if (tl >= 0) {
            float4 pv = P4[tl * W4 + xl], qv = Q4[tl * W4 + xl], iv = I4[tl * W4 + xl];
            sp.x -= pv.x; sp.y -= pv.y; sp.z -= pv.z; sp.w -= pv.w;
            sqq.x -= qv.x; sqq.y -= qv.y; sqq.z -= qv.z; sqq.w -= qv.w;
            sm.x -= (iv.x > MASK_THRf) ? 1.f : 0.f;
            sm.y -= (iv.y > MASK_THRf) ? 1.f : 0.f;
            sm.z -= (iv.z > MASK_THRf) ? 1.f : 0.f;
            sm.w -= (iv.w > MASK_THRf) ? 1.f : 0.f;
        }
        float4 vP = inb ? sp : f4zero();
        float4 vQ = inb ? sqq : f4zero();
        float4 vM = inb ? sm : f4zero();
        float4 bP = hbox(vP, lane);
        float4 bQ = hbox(vQ, lane);
        float4 bM = hbox(vM, lane);
        if (inb && lane >= 3 && lane <= 60) {
            int xo = y * W4 + xc;
            float4 Iv = I4[xo], Bv = B4[xo];     // I[y] inside window: cache hit
            {
                float rn = rcpf(bM.x + EPSf);
                float bd = bP.x * rn, db = bQ.x * rn;
                float m = (Iv.x > MASK_THRf) ? 1.f : 0.f;
                bd = bd * m + (1.f - m); db = db * m + (1.f - m);
                float d = Bv.x - bd * rcpf(db + EPSf); a += d * d;
            }
            {
                float rn = rcpf(bM.y + EPSf);
                float bd = bP.y * rn, db = bQ.y * rn;
                float m = (Iv.y > MASK_THRf) ? 1.f : 0.f;
                bd = bd * m + (1.f - m); db = db * m + (1.f - m);
                float d = Bv.y - bd * rcpf(db + EPSf); a += d * d;
            }
            {
                float rn = rcpf(bM.z + EPSf);
                float bd = bP.z * rn, db = bQ.z * rn;
                float m = (Iv.z > MASK_THRf) ? 1.f : 0.f;
                bd = bd * m + (1.f - m); db = db * m + (1.f - m);
                float d = Bv.z - bd * rcpf(db + EPSf); a += d * d;
            }
            {
                float rn = rcpf(bM.w + EPSf);
                float bd = bP.w * rn, db = bQ.w * rn;
                float m = (Iv.w > MASK_THRf) ? 1.f : 0.f;
                bd = bd * m + (1.f - m); db = db * m + (1.f - m);
                float d = Bv.w - bd * rcpf(db + EPSf); a += d * d;
            }
        }
    }

    a = waveReduce(a);
    if (lane == 0) partL[wid] = a;
}

// ---------------- k6: reduce per-wave loss partials, write mean ----------------
__global__ __launch_bounds__(1024) void k6_out(const float* __restrict__ partL, float* __restrict__ out) {
    __shared__ float s[1024];
    int tid = threadIdx.x;
    float acc = 0.f;
    for (int c = tid; c < NWAVE; c += 1024) acc += partL[c];
    s[tid] = acc;
    __syncthreads();
    #pragma unroll
    for (int st = 512; st >= 1; st >>= 1) {
        if (tid < st) s[tid] += s[tid + st];
        __syncthreads();
    }
    if (tid == 0) out[0] = s[0] / (float)NN;
}

extern "C" void kernel_launch(void* const* d_in, const int* in_sizes, int n_in,
                              void* d_out, int out_size, void* d_ws, size_t ws_size,
                              hipStream_t stream) {
    const float* I = (const float*)d_in[0];
    const float* U = (const float*)d_in[1];
    const float* B = (const float*)d_in[2];
    const float* E = (const float*)d_in[3];
    // p=2, size=21 fixed by setup_inputs; hard-coded.

    float* P     = (float*)d_ws;        // [NN]
    float* Q     = P + NN;              // [NN]
    float* partA = Q + NN;              // NWAVE*8
    float* partL = partA + NWAVE * 8;   // NWAVE
    float* vV    = partL + NWAVE;       // v0..v3

    kA<<<NWAVE, 64, 0, stream>>>(I, B, E, U, partA);
    k3_v<<<1, 1024, 0, stream>>>(partA, vV);
    kP<<<NN4 / 256, 256, 0, stream>>>(I, E, U, vV, P, Q);
    kB<<<NWAVE, 64, 0, stream>>>(P, Q, I, B, partL);
    k6_out<<<1, 1024, 0, stream>>>(partL, (float*)d_out);
}

// Round 6
// 225.631 us; speedup vs baseline: 1.1955x; 1.1076x over previous
//
#include <hip/hip_runtime.h>

constexpr int Hh = 2048;
constexpr int Ww = 2048;
constexpr int NN = Hh * Ww;
constexpr int W4 = Ww / 4;             // row stride in float4
constexpr int NN4 = NN / 4;            // plane stride in float4
constexpr int RAD = 10;                // size=21 -> radius 10
constexpr float EPSf = 1e-9f;
constexpr float MASK_THRf = 0.001f;
constexpr int SEGW = 58;               // output float4 cols per wave (64 - 2*3 halo)
constexpr int NSEG = 9;                // ceil(W4 / SEGW)
constexpr int BH = 8;                  // rows walked per wave (was 16; halved for 2x TLP)
constexpr int NBAND = Hh / BH;         // 256 bands
constexpr int NWAVE = NSEG * NBAND;    // 2304 wave-items -> 9 waves/CU

__device__ inline float rcpf(float x) { return __builtin_amdgcn_rcpf(x); }

__device__ inline float waveReduce(float v) {
    #pragma unroll
    for (int o = 32; o > 0; o >>= 1) v += __shfl_down(v, o, 64);
    return v;
}

__device__ inline float4 f4zero() { float4 z; z.x = z.y = z.z = z.w = 0.f; return z; }

// Direct 21-tap horizontal box of v (zero outside the wave's halo) via
// neighbor-lane shuffles. Valid only for lanes 3..60 (halo lanes discarded).
__device__ inline float4 hbox(float4 v, int lane) {
    float S = v.x + v.y + v.z + v.w;
    float Sm2 = __shfl(S, lane - 2, 64);
    float Sm1 = __shfl(S, lane - 1, 64);
    float Sp1 = __shfl(S, lane + 1, 64);
    float Sp2 = __shfl(S, lane + 2, 64);
    float T5 = Sm2 + Sm1 + S + Sp1 + Sp2;
    float wm3 = __shfl(v.w, lane - 3, 64);
    float zm3 = __shfl(v.z, lane - 3, 64);
    float xm2 = __shfl(v.x, lane - 2, 64);
    float wp2 = __shfl(v.w, lane + 2, 64);
    float xp3 = __shfl(v.x, lane + 3, 64);
    float yp3 = __shfl(v.y, lane + 3, 64);
    float4 r;
    r.y = T5 + wm3;
    r.z = T5 + xp3;
    r.x = r.y + zm3 - wp2;
    r.w = r.z + yp3 - xm2;
    return r;
}

// Weighted window update, f in {+1, -1, 0} (wave-uniform). Terms are computed
// with identical expressions on add (+1) and subtract (-1) paths; fma by +-1.0
// is exact, so the sliding window cancels each row's contribution bit-exactly.
// f=0 rows (clamped OOB loads) contribute exactly nothing.
__device__ inline void winA(float4& sm, float4& sb, float4& sq,
                            float4 iv, float4 bv, float f) {
    sm.x += f * ((iv.x > MASK_THRf) ? 1.f : 0.f);
    sm.y += f * ((iv.y > MASK_THRf) ? 1.f : 0.f);
    sm.z += f * ((iv.z > MASK_THRf) ? 1.f : 0.f);
    sm.w += f * ((iv.w > MASK_THRf) ? 1.f : 0.f);
    sb.x += f * bv.x; sb.y += f * bv.y; sb.z += f * bv.z; sb.w += f * bv.w;
    sq.x += f * (bv.x * bv.x); sq.y += f * (bv.y * bv.y);
    sq.z += f * (bv.z * bv.z); sq.w += f * (bv.w * bv.w);
}

__device__ inline void winB(float4& sp, float4& sq, float4& sm,
                            float4 pv, float4 qv, float4 iv, float f) {
    sp.x += f * pv.x; sp.y += f * pv.y; sp.z += f * pv.z; sp.w += f * pv.w;
    sq.x += f * qv.x; sq.y += f * qv.y; sq.z += f * qv.z; sq.w += f * qv.w;
    sm.x += f * ((iv.x > MASK_THRf) ? 1.f : 0.f);
    sm.y += f * ((iv.y > MASK_THRf) ? 1.f : 0.f);
    sm.z += f * ((iv.z > MASK_THRf) ? 1.f : 0.f);
    sm.w += f * ((iv.w > MASK_THRf) ? 1.f : 0.f);
}

__device__ inline void k2_pix(float bm, float bb, float bb2, float Iv, float ev,
                              float u0, float u1, float u2, float u3, float* a) {
    float rn = rcpf(bm + EPSf);
    float bK = bb * rn;
    float b2K = bb2 * rn;
    float p0 = u0 * u0, p1 = u1 * u1, p2 = u2 * u2, p3 = u3 * u3;
    a[0] += Iv * p0;
    a[1] += p0;
    float A = (Iv - ev) * bK;
    a[2] += A * p1; a[3] += A * p2; a[4] += A * p3;
    a[5] += b2K * p1; a[6] += b2K * p2; a[7] += b2K * p3;
}

// ---------------- kA: fused vertical window + h-box + phase-A reductions ----------------
// Unroll-2 row loop with ALL loads hoisted unconditionally (clamped addresses,
// weighted contributions) -> ~20 independent float4 loads in flight per iter.
__global__ __launch_bounds__(64, 2) void kA(
        const float* __restrict__ I, const float* __restrict__ B,
        const float* __restrict__ E, const float* __restrict__ U,
        float* __restrict__ partA) {
    int lane = threadIdx.x;
    int wid = blockIdx.x;
    int strip = wid % NSEG;              // adjacent blocks share a band -> row locality
    int band = wid / NSEG;
    int xc = strip * SEGW - 3 + lane;
    bool inb = (unsigned)xc < (unsigned)W4;
    int xl = inb ? xc : 0;
    int y0 = band * BH;

    const float4* I4 = (const float4*)I;
    const float4* B4 = (const float4*)B;
    const float4* E4 = (const float4*)E;
    const float4* U0 = (const float4*)U;
    const float4* U1 = U0 + NN4;
    const float4* U2 = U1 + NN4;
    const float4* U3 = U2 + NN4;

    float4 sm = f4zero(), sb = f4zero(), sq = f4zero();
    // prime with window(y0-1) = rows [y0-11, y0+9]
    #pragma unroll
    for (int k = 0; k < 2 * RAD + 1; ++k) {
        int r = y0 - RAD - 1 + k;
        float f = ((unsigned)r < (unsigned)Hh) ? 1.f : 0.f;
        int rc = (r < 0) ? 0 : ((r > Hh - 1) ? Hh - 1 : r);
        winA(sm, sb, sq, I4[rc * W4 + xl], B4[rc * W4 + xl], f);
    }

    float a[8] = {0, 0, 0, 0, 0, 0, 0, 0};
    #pragma unroll 1
    for (int yy = 0; yy < BH; yy += 2) {
        int y = y0 + yy;
        int hd0 = y + RAD, hd1 = y + RAD + 1;
        int tl0 = y - RAD - 1, tl1 = y - RAD;
        float fh0 = (hd0 < Hh) ? 1.f : 0.f;
        float fh1 = (hd1 < Hh) ? 1.f : 0.f;
        float ft0 = (tl0 >= 0) ? -1.f : 0.f;
        float ft1 = (tl1 >= 0) ? -1.f : 0.f;
        int rh0 = (hd0 < Hh) ? hd0 : Hh - 1;
        int rh1 = (hd1 < Hh) ? hd1 : Hh - 1;
        int rt0 = (tl0 >= 0) ? tl0 : 0;
        int rt1 = (tl1 >= 0) ? tl1 : 0;
        // ---- all loads for both rows, independent ----
        float4 ih0 = I4[rh0 * W4 + xl], bh0 = B4[rh0 * W4 + xl];
        float4 ih1 = I4[rh1 * W4 + xl], bh1 = B4[rh1 * W4 + xl];
        float4 it0 = I4[rt0 * W4 + xl], bt0 = B4[rt0 * W4 + xl];
        float4 it1 = I4[rt1 * W4 + xl], bt1 = B4[rt1 * W4 + xl];
        int xo0 = y * W4 + xl, xo1 = (y + 1) * W4 + xl;
        float4 Iv0 = I4[xo0], Ev0 = E4[xo0];
        float4 u00 = U0[xo0], u10 = U1[xo0], u20 = U2[xo0], u30 = U3[xo0];
        float4 Iv1 = I4[xo1], Ev1 = E4[xo1];
        float4 u01 = U0[xo1], u11 = U1[xo1], u21 = U2[xo1], u31 = U3[xo1];
        // ---- row y ----
        winA(sm, sb, sq, ih0, bh0, fh0);
        winA(sm, sb, sq, it0, bt0, ft0);
        {
            float4 vm = inb ? sm : f4zero();
            float4 vb = inb ? sb : f4zero();
            float4 vq = inb ? sq : f4zero();
            float4 bm = hbox(vm, lane);
            float4 bb = hbox(vb, lane);
            float4 bq = hbox(vq, lane);
            if (inb && lane >= 3 && lane <= 60) {
                k2_pix(bm.x, bb.x, bq.x, Iv0.x, Ev0.x, u00.x, u10.x, u20.x, u30.x, a);
                k2_pix(bm.y, bb.y, bq.y, Iv0.y, Ev0.y, u00.y, u10.y, u20.y, u30.y, a);
                k2_pix(bm.z, bb.z, bq.z, Iv0.z, Ev0.z, u00.z, u10.z, u20.z, u30.z, a);
                k2_pix(bm.w, bb.w, bq.w, Iv0.w, Ev0.w, u00.w, u10.w, u20.w, u30.w, a);
            }
        }
        // ---- row y+1 ----
        winA(sm, sb, sq, ih1, bh1, fh1);
        winA(sm, sb, sq, it1, bt1, ft1);
        {
            float4 vm = inb ? sm : f4zero();
            float4 vb = inb ? sb : f4zero();
            float4 vq = inb ? sq : f4zero();
            float4 bm = hbox(vm, lane);
            float4 bb = hbox(vb, lane);
            float4 bq = hbox(vq, lane);
            if (inb && lane >= 3 && lane <= 60) {
                k2_pix(bm.x, bb.x, bq.x, Iv1.x, Ev1.x, u01.x, u11.x, u21.x, u31.x, a);
                k2_pix(bm.y, bb.y, bq.y, Iv1.y, Ev1.y, u01.y, u11.y, u21.y, u31.y, a);
                k2_pix(bm.z, bb.z, bq.z, Iv1.z, Ev1.z, u01.z, u11.z, u21.z, u31.z, a);
                k2_pix(bm.w, bb.w, bq.w, Iv1.w, Ev1.w, u01.w, u11.w, u21.w, u31.w, a);
            }
        }
    }

    #pragma unroll
    for (int k = 0; k < 8; ++k) a[k] = waveReduce(a[k]);
    if (lane == 0) {
        float4 r0, r1;
        r0.x = a[0]; r0.y = a[1]; r0.z = a[2]; r0.w = a[3];
        r1.x = a[4]; r1.y = a[5]; r1.z = a[6]; r1.w = a[7];
        ((float4*)partA)[wid * 2]     = r0;
        ((float4*)partA)[wid * 2 + 1] = r1;
    }
}

// ---------------- k3: reduce per-wave partials (NWAVE x 8), compute v ----------------
__global__ __launch_bounds__(1024) void k3_v(const float* __restrict__ partA, float* __restrict__ vV) {
    __shared__ float s[1024];
    int tid = threadIdx.x;
    float acc = 0.f;
    #pragma unroll
    for (int j = 0; j < (NWAVE * 8) / 1024; ++j) acc += partA[tid + j * 1024];
    s[tid] = acc;
    __syncthreads();
    #pragma unroll
    for (int st = 512; st >= 8; st >>= 1) {
        if (tid < st) s[tid] += s[tid + st];
        __syncthreads();
    }
    if (tid == 0) {
        vV[0] = s[0] / (s[1] + EPSf);
        vV[1] = s[2] / (s[5] + EPSf);
        vV[2] = s[3] / (s[6] + EPSf);
        vV[3] = s[4] / (s[7] + EPSf);
    }
}

// ---------------- kP: elementwise P = (I-e)*sum(v*u^2), Q = sum(v^2*u^2) ----------------
__global__ __launch_bounds__(256) void kP(
        const float* __restrict__ I, const float* __restrict__ E, const float* __restrict__ U,
        const float* __restrict__ vV,
        float* __restrict__ P, float* __restrict__ Q) {
    int idx = blockIdx.x * 256 + threadIdx.x;    // float4 index, grid covers NN4 exactly
    float v0 = vV[0], v1 = vV[1], v2 = vV[2], v3 = vV[3];
    float w0 = v0 * v0, w1 = v1 * v1, w2 = v2 * v2, w3 = v3 * v3;
    const float4* I4 = (const float4*)I;
    const float4* E4 = (const float4*)E;
    const float4* U0 = (const float4*)U;
    const float4* U1 = U0 + NN4;
    const float4* U2 = U1 + NN4;
    const float4* U3 = U2 + NN4;
    float4 Iv = I4[idx], Ev = E4[idx];
    float4 a0 = U0[idx], a1 = U1[idx], a2 = U2[idx], a3 = U3[idx];
    float4 p, q;
    float p0, p1, p2, p3;
    p0 = a0.x * a0.x; p1 = a1.x * a1.x; p2 = a2.x * a2.x; p3 = a3.x * a3.x;
    p.x = (Iv.x - Ev.x) * (v0 * p0 + v1 * p1 + v2 * p2 + v3 * p3);
    q.x = w0 * p0 + w1 * p1 + w2 * p2 + w3 * p3;
    p0 = a0.y * a0.y; p1 = a1.y * a1.y; p2 = a2.y * a2.y; p3 = a3.y * a3.y;
    p.y = (Iv.y - Ev.y) * (v0 * p0 + v1 * p1 + v2 * p2 + v3 * p3);
    q.y = w0 * p0 + w1 * p1 + w2 * p2 + w3 * p3;
    p0 = a0.z * a0.z; p1 = a1.z * a1.z; p2 = a2.z * a2.z; p3 = a3.z * a3.z;
    p.z = (Iv.z - Ev.z) * (v0 * p0 + v1 * p1 + v2 * p2 + v3 * p3);
    q.z = w0 * p0 + w1 * p1 + w2 * p2 + w3 * p3;
    p0 = a0.w * a0.w; p1 = a1.w * a1.w; p2 = a2.w * a2.w; p3 = a3.w * a3.w;
    p.w = (Iv.w - Ev.w) * (v0 * p0 + v1 * p1 + v2 * p2 + v3 * p3);
    q.w = w0 * p0 + w1 * p1 + w2 * p2 + w3 * p3;
    ((float4*)P)[idx] = p;
    ((float4*)Q)[idx] = q;
}

// ---------------- kB: fused vertical window over (P,Q,mask) + h-box + loss ----------------
__global__ __launch_bounds__(64, 2) void kB(
        const float* __restrict__ P, const float* __restrict__ Q,
        const float* __restrict__ I, const float* __restrict__ B,
        float* __restrict__ partL) {
    int lane = threadIdx.x;
    int wid = blockIdx.x;
    int strip = wid % NSEG;
    int band = wid / NSEG;
    int xc = strip * SEGW - 3 + lane;
    bool inb = (unsigned)xc < (unsigned)W4;
    int xl = inb ? xc : 0;
    int y0 = band * BH;

    const float4* P4 = (const float4*)P;
    const float4* Q4 = (const float4*)Q;
    const float4* I4 = (const float4*)I;
    const float4* B4 = (const float4*)B;

    float4 sp = f4zero(), sqq = f4zero(), sm = f4zero();
    #pragma unroll
    for (int k = 0; k < 2 * RAD + 1; ++k) {
        int r = y0 - RAD - 1 + k;
        float f = ((unsigned)r < (unsigned)Hh) ? 1.f : 0.f;
        int rc = (r < 0) ? 0 : ((r > Hh - 1) ? Hh - 1 : r);
        winB(sp, sqq, sm, P4[rc * W4 + xl], Q4[rc * W4 + xl], I4[rc * W4 + xl], f);
    }

    float a = 0.f;
    #pragma unroll 1
    for (int yy = 0; yy < BH; yy += 2) {
        int y = y0 + yy;
        int hd0 = y + RAD, hd1 = y + RAD + 1;
        int tl0 = y - RAD - 1, tl1 = y - RAD;
        float fh0 = (hd0 < Hh) ? 1.f : 0.f;
        float fh1 = (hd1 < Hh) ? 1.f : 0.f;
        float ft0 = (tl0 >= 0) ? -1.f : 0.f;
        float ft1 = (tl1 >= 0) ? -1.f : 0.f;
        int rh0 = (hd0 < Hh) ? hd0 : Hh - 1;
        int rh1 = (hd1 < Hh) ? hd1 : Hh - 1;
        int rt0 = (tl0 >= 0) ? tl0 : 0;
        int rt1 = (tl1 >= 0) ? tl1 : 0;
        // ---- all loads for both rows ----
        float4 ph0 = P4[rh0 * W4 + xl], qh0 = Q4[rh0 * W4 + xl], mh0 = I4[rh0 * W4 + xl];
        float4 ph1 = P4[rh1 * W4 + xl], qh1 = Q4[rh1 * W4 + xl], mh1 = I4[rh1 * W4 + xl];
        float4 pt0 = P4[rt0 * W4 + xl], qt0 = Q4[rt0 * W4 + xl], mt0 = I4[rt0 * W4 + xl];
        float4 pt1 = P4[rt1 * W4 + xl], qt1 = Q4[rt1 * W4 + xl], mt1 = I4[rt1 * W4 + xl];
        int xo0 = y * W4 + xl, xo1 = (y + 1) * W4 + xl;
        float4 Iv0 = I4[xo0], Bv0 = B4[xo0];
        float4 Iv1 = I4[xo1], Bv1 = B4[xo1];
        // ---- row y ----
        winB(sp, sqq, sm, ph0, qh0, mh0, fh0);
        winB(sp, sqq, sm, pt0, qt0, mt0, ft0);
        {
            float4 vP = inb ? sp : f4zero();
            float4 vQ = inb ? sqq : f4zero();
            float4 vM = inb ? sm : f4zero();
            float4 bP = hbox(vP, lane);
            float4 bQ = hbox(vQ, lane);
            float4 bM = hbox(vM, lane);
            if (inb && lane >= 3 && lane <= 60) {
                {
                    float rn = rcpf(bM.x + EPSf);
                    float bd = bP.x * rn, db = bQ.x * rn;
                    float m = (Iv0.x > MASK_THRf) ? 1.f : 0.f;
                    bd = bd * m + (1.f - m); db = db * m + (1.f - m);
                    float d = Bv0.x - bd * rcpf(db + EPSf); a += d * d;
                }
                {
                    float rn = rcpf(bM.y + EPSf);
                    float bd = bP.y * rn, db = bQ.y * rn;
                    float m = (Iv0.y > MASK_THRf) ? 1.f : 0.f;
                    bd = bd * m + (1.f - m); db = db * m + (1.f - m);
                    float d = Bv0.y - bd * rcpf(db + EPSf); a += d * d;
                }
                {
                    float rn = rcpf(bM.z + EPSf);
                    float bd = bP.z * rn, db = bQ.z * rn;
                    float m = (Iv0.z > MASK_THRf) ? 1.f : 0.f;
                    bd = bd * m + (1.f - m); db = db * m + (1.f - m);
                    float d = Bv0.z - bd * rcpf(db + EPSf); a += d * d;
                }
                {
                    float rn = rcpf(bM.w + EPSf);
                    float bd = bP.w * rn, db = bQ.w * rn;
                    float m = (Iv0.w > MASK_THRf) ? 1.f : 0.f;
                    bd = bd * m + (1.f - m); db = db * m + (1.f - m);
                    float d = Bv0.w - bd * rcpf(db + EPSf); a += d * d;
                }
            }
        }
        // ---- row y+1 ----
        winB(sp, sqq, sm, ph1, qh1, mh1, fh1);
        winB(sp, sqq, sm, pt1, qt1, mt1, ft1);
        {
            float4 vP = inb ? sp : f4zero();
            float4 vQ = inb ? sqq : f4zero();
            float4 vM = inb ? sm : f4zero();
            float4 bP = hbox(vP, lane);
            float4 bQ = hbox(vQ, lane);
            float4 bM = hbox(vM, lane);
            if (inb && lane >= 3 && lane <= 60) {
                {
                    float rn = rcpf(bM.x + EPSf);
                    float bd = bP.x * rn, db = bQ.x * rn;
                    float m = (Iv1.x > MASK_THRf) ? 1.f : 0.f;
                    bd = bd * m + (1.f - m); db = db * m + (1.f - m);
                    float d = Bv1.x - bd * rcpf(db + EPSf); a += d * d;
                }
                {
                    float rn = rcpf(bM.y + EPSf);
                    float bd = bP.y * rn, db = bQ.y * rn;
                    float m = (Iv1.y > MASK_THRf) ? 1.f : 0.f;
                    bd = bd * m + (1.f - m); db = db * m + (1.f - m);
                    float d = Bv1.y - bd * rcpf(db + EPSf); a += d * d;
                }
                {
                    float rn = rcpf(bM.z + EPSf);
                    float bd = bP.z * rn, db = bQ.z * rn;
                    float m = (Iv1.z > MASK_THRf) ? 1.f : 0.f;
                    bd = bd * m + (1.f - m); db = db * m + (1.f - m);
                    float d = Bv1.z - bd * rcpf(db + EPSf); a += d * d;
                }
                {
                    float rn = rcpf(bM.w + EPSf);
                    float bd = bP.w * rn, db = bQ.w * rn;
                    float m = (Iv1.w > MASK_THRf) ? 1.f : 0.f;
                    bd = bd * m + (1.f - m); db = db * m + (1.f - m);
                    float d = Bv1.w - bd * rcpf(db + EPSf); a += d * d;
                }
            }
        }
    }

    a = waveReduce(a);
    if (lane == 0) partL[wid] = a;
}

// ---------------- k6: reduce per-wave loss partials, write mean ----------------
__global__ __launch_bounds__(1024) void k6_out(const float* __restrict__ partL, float* __restrict__ out) {
    __shared__ float s[1024];
    int tid = threadIdx.x;
    float acc = 0.f;
    for (int c = tid; c < NWAVE; c += 1024) acc += partL[c];
    s[tid] = acc;
    __syncthreads();
    #pragma unroll
    for (int st = 512; st >= 1; st >>= 1) {
        if (tid < st) s[tid] += s[tid + st];
        __syncthreads();
    }
    if (tid == 0) out[0] = s[0] / (float)NN;
}

extern "C" void kernel_launch(void* const* d_in, const int* in_sizes, int n_in,
                              void* d_out, int out_size, void* d_ws, size_t ws_size,
                              hipStream_t stream) {
    const float* I = (const float*)d_in[0];
    const float* U = (const float*)d_in[1];
    const float* B = (const float*)d_in[2];
    const float* E = (const float*)d_in[3];
    // p=2, size=21 fixed by setup_inputs; hard-coded.

    float* P     = (float*)d_ws;        // [NN]
    float* Q     = P + NN;              // [NN]
    float* partA = Q + NN;              // NWAVE*8
    float* partL = partA + NWAVE * 8;   // NWAVE
    float* vV    = partL + NWAVE;       // v0..v3

    kA<<<NWAVE, 64, 0, stream>>>(I, B, E, U, partA);
    k3_v<<<1, 1024, 0, stream>>>(partA, vV);
    kP<<<NN4 / 256, 256, 0, stream>>>(I, E, U, vV, P, Q);
    kB<<<NWAVE, 64, 0, stream>>>(P, Q, I, B, partL);
    k6_out<<<1, 1024, 0, stream>>>(partL, (float*)d_out);
}